// Round 20
// baseline (575.108 us; speedup 1.0000x reference)
//
#include <hip/hip_runtime.h>
#include <hip/hip_bf16.h>
#include <cstdint>

typedef __attribute__((ext_vector_type(8))) __bf16 bf16x8;
typedef __attribute__((ext_vector_type(4))) float f32x4;
typedef unsigned short u16t;

constexpr int Bn = 8, Dn = 768, Tn = 1024, Hn = 8, DHn = 96, FFn = 3072;
constexpr int BT = Bn * Tn; // 8192
constexpr float INV_SQRT_DH_L2E = 0.14724444927f; // (1/sqrt(96)) * log2(e)
constexpr float L2E = 1.4426950408889634f;
constexpr float THR_L2E = 11.541560327f;          // 8 * log2(e)
constexpr float GEL_C = -2.0f * 0.7978845608f * L2E; // -2*sqrt(2/pi)*log2(e)

#define GLDS16(gp, lp) __builtin_amdgcn_global_load_lds( \
    (__attribute__((address_space(1))) unsigned int*)(uintptr_t)(gp), \
    (__attribute__((address_space(3))) unsigned int*)(uintptr_t)(lp), 16, 0, 0)

// bare v_exp_f32 (2^x). underflow->0, overflow->inf; both give correct sigmoid limits.
__device__ __forceinline__ float ex2(float x) {
  float r;
  asm("v_exp_f32 %0, %1" : "=v"(r) : "v"(x));
  return r;
}

// ---------------- merged weight prep (one launch) ----------------
__global__ void k_prep(const float* __restrict__ w_ff1a, const float* __restrict__ w_ff1b,
                       const float* __restrict__ w_qkv, const float* __restrict__ w_out,
                       const float* __restrict__ w_ff2a, const float* __restrict__ w_ff2b,
                       const float* __restrict__ pw1_w, const float* __restrict__ pw2_w,
                       const float* __restrict__ rel_embed,
                       __hip_bfloat16* __restrict__ Wf1a, __hip_bfloat16* __restrict__ Wf1b,
                       __hip_bfloat16* __restrict__ Wqkv, __hip_bfloat16* __restrict__ Wout,
                       __hip_bfloat16* __restrict__ Wf2a, __hip_bfloat16* __restrict__ Wf2b,
                       __hip_bfloat16* __restrict__ Wpw1, __hip_bfloat16* __restrict__ Wpw2,
                       float* __restrict__ rel_tab,
                       float* __restrict__ gs1, float* __restrict__ gs2) {
  __shared__ float t[32][33];
  const int tid = threadIdx.x;
  int bid = blockIdx.x;

  const float* tsrc = nullptr;
  __hip_bfloat16* tdst = nullptr;
  int K = 0, N = 0;
  if (bid < 2304) { tsrc = w_ff1a; tdst = Wf1a; K = 768; N = 3072; }
  else if ((bid -= 2304) < 2304) { tsrc = w_ff1b; tdst = Wf1b; K = 3072; N = 768; }
  else if ((bid -= 2304) < 1728) { tsrc = w_qkv; tdst = Wqkv; K = 768; N = 2304; }
  else if ((bid -= 1728) < 576)  { tsrc = w_out; tdst = Wout; K = 768; N = 768; }
  else if ((bid -= 576) < 2304)  { tsrc = w_ff2a; tdst = Wf2a; K = 768; N = 3072; }
  else if ((bid -= 2304) < 2304) { tsrc = w_ff2b; tdst = Wf2b; K = 3072; N = 768; }
  else {
    bid -= 2304;
    if (bid < 1152) { // pw1 interleave
      int i4 = bid * 1024 + tid * 4;
      int n = i4 / 768, k = i4 - n * 768;
      int on = (n >> 1) + (n & 1) * 768;
      float4 v = *(const float4*)(pw1_w + (size_t)on * 768 + k);
      __hip_bfloat16* d = Wpw1 + i4;
      d[0] = __float2bfloat16(v.x); d[1] = __float2bfloat16(v.y);
      d[2] = __float2bfloat16(v.z); d[3] = __float2bfloat16(v.w);
    } else if ((bid -= 1152) < 576) { // pw2 convert
      int i4 = bid * 1024 + tid * 4;
      float4 v = *(const float4*)(pw2_w + i4);
      __hip_bfloat16* d = Wpw2 + i4;
      d[0] = __float2bfloat16(v.x); d[1] = __float2bfloat16(v.y);
      d[2] = __float2bfloat16(v.z); d[3] = __float2bfloat16(v.w);
    } else { // rel table + GN-sum zeroing
      bid -= 576;
      if (bid == 0) {
        if (tid < 16) gs1[tid] = 0.0f;
        else if (tid < 32) gs2[tid - 16] = 0.0f;
      }
      int dd = bid * 256 + tid;
      if (dd < 2047) {
        int d = dd - 1023;
        int sign = d >= 0 ? 1 : 0;
        int ra = d < 0 ? -d : d;
        int base;
        if (ra < 80) base = ra;
        else {
          float lr = logf((float)ra / 80.0f) / 2.3025851f;
          int lp = 80 + (int)(lr * 80.0f);
          base = lp < 159 ? lp : 159;
        }
        int bucket = base + sign * 160;
        if (bucket < 0) bucket = 0;
        if (bucket > 319) bucket = 319;
        for (int h = 0; h < 8; ++h)
          rel_tab[h * 2047 + dd] = rel_embed[bucket * 8 + h];
      }
    }
    return;
  }
  int nb32 = N / 32;
  int nb = (bid % nb32) * 32, kb = (bid / nb32) * 32;
  int tx = tid & 31, ty = tid >> 5;
  for (int i = ty; i < 32; i += 8)
    t[i][tx] = tsrc[(size_t)(kb + i) * N + nb + tx];
  __syncthreads();
  for (int i = ty; i < 32; i += 8)
    tdst[(size_t)(nb + i) * K + kb + tx] = __float2bfloat16(t[tx][i]);
}

// ---------------- transposes ----------------
__global__ void k_tin(const float* __restrict__ x, float* __restrict__ s,
                      __hip_bfloat16* __restrict__ sb) {
  __shared__ float t[32][33];
  int b = blockIdx.z;
  int t0 = blockIdx.x * 32, d0 = blockIdx.y * 32;
  int tx = threadIdx.x, ty = threadIdx.y;
  for (int i = ty; i < 32; i += 8)
    t[i][tx] = x[((size_t)b * Dn + d0 + i) * Tn + t0 + tx];
  __syncthreads();
  for (int i = ty; i < 32; i += 8) {
    float v = t[tx][i];
    size_t o = (size_t)(b * Tn + t0 + i) * Dn + d0 + tx;
    s[o] = v;
    sb[o] = __float2bfloat16(v);
  }
}

// V part of qkv -> VT[(b*8+h)*96 + d][1024]
__global__ void k_vtrans(const __hip_bfloat16* __restrict__ qkv,
                         __hip_bfloat16* __restrict__ VT) {
  __shared__ __hip_bfloat16 t[32][33];
  int bh = blockIdx.z;
  int b = bh >> 3, h = bh & 7;
  int t0 = blockIdx.x * 32, d0 = blockIdx.y * 32;
  int tx = threadIdx.x, ty = threadIdx.y;
  for (int i = ty; i < 32; i += 8)
    t[i][tx] = qkv[(size_t)(b * Tn + t0 + i) * 2304 + 1536 + h * 96 + d0 + tx];
  __syncthreads();
  for (int i = ty; i < 32; i += 8)
    VT[((size_t)bh * 96 + d0 + i) * Tn + t0 + tx] = t[tx][i];
}

// ---------------- GEMM: C = A[M,K] * Bt[N,K]^T, bf16 in, fp32 acc ----------------
enum { EPI_BIAS = 0, EPI_GELU = 1, EPI_HALF_RES = 2, EPI_RES = 3, EPI_GLU = 4,
       EPI_HALF_RES_T = 5 };

template <int BM, int BN, int DEPTH, int EPI, bool GNACC>
__global__ __launch_bounds__(256)
void k_gemm(const __hip_bfloat16* __restrict__ A, const __hip_bfloat16* __restrict__ Bt,
            const float* __restrict__ bias, const float* __restrict__ resid,
            float* __restrict__ outF, __hip_bfloat16* __restrict__ outB,
            float* __restrict__ gsum, int M, int N, int K) {
  constexpr int MI = BM / 32;
  constexpr int NI = BN / 32;
  constexpr int ASZ = BM * 32;
  constexpr int BSZ = BN * 32;
  constexpr int STG_BYTES = 2 * DEPTH * (ASZ + BSZ) * 2;
  constexpr int TR_BYTES = (EPI == EPI_HALF_RES_T) ? BN * 72 * 4 : 0;
  constexpr int SMEM_BYTES = (TR_BYTES > STG_BYTES) ? TR_BYTES : STG_BYTES;
  __shared__ __align__(16) char smem[SMEM_BYTES];
  __hip_bfloat16* lAp = (__hip_bfloat16*)smem;
  __hip_bfloat16* lBp = (__hip_bfloat16*)(smem + (size_t)2 * DEPTH * ASZ * 2);

  const int tid = threadIdx.x;
  const int lane = tid & 63, wv = tid >> 6;
  const int g = lane >> 4, c15 = lane & 15;
  const int gx = gridDim.x;
  const int nwg = gx * gridDim.y;
  const int orig = blockIdx.y * gx + blockIdx.x;
  const int q = nwg >> 3, rr = nwg & 7;
  const int xcd = orig & 7, idx = orig >> 3;
  const int wg = (xcd < rr ? xcd * (q + 1) : rr * (q + 1) + (xcd - rr) * q) + idx;
  const int m0 = (wg / gx) * BM, n0 = (wg % gx) * BN;
  const int wm = (wv >> 1) * (BM / 2), wn = (wv & 1) * (BN / 2);

  const int srow = lane >> 2, scol = (lane & 3) * 8;

  f32x4 acc[MI][NI] = {};

  auto stage = [&](int buf, int kt) {
#pragma unroll
    for (int c = 0; c < BM / 64; ++c) {
      int cid = wv * (BM / 64) + c;
      GLDS16(A + (size_t)(m0 + cid * 16 + srow) * K + kt + scol, lAp + buf * ASZ + cid * 512);
    }
#pragma unroll
    for (int c = 0; c < BN / 64; ++c) {
      int cid = wv * (BN / 64) + c;
      GLDS16(Bt + (size_t)(n0 + cid * 16 + srow) * K + kt + scol, lBp + buf * BSZ + cid * 512);
    }
  };

  auto compute = [&](int buf) {
    bf16x8 af[MI], bfr[NI];
#pragma unroll
    for (int i = 0; i < MI; ++i)
      af[i] = *(const bf16x8*)&lAp[buf * ASZ + (wm + i * 16 + c15) * 32 + g * 8];
#pragma unroll
    for (int j = 0; j < NI; ++j)
      bfr[j] = *(const bf16x8*)&lBp[buf * BSZ + (wn + j * 16 + c15) * 32 + g * 8];
#pragma unroll
    for (int i = 0; i < MI; ++i)
#pragma unroll
      for (int j = 0; j < NI; ++j)
        acc[i][j] = __builtin_amdgcn_mfma_f32_16x16x32_bf16(af[i], bfr[j], acc[i][j], 0, 0, 0);
  };

  const int nt = K >> 5;
  if constexpr (DEPTH == 1) {
    stage(0, 0);
    __syncthreads();
    int cur = 0;
    for (int t = 0; t < nt; ++t) {
      if (t + 1 < nt) stage(cur ^ 1, (t + 1) * 32);
      compute(cur);
      __syncthreads();
      cur ^= 1;
    }
  } else {
    stage(0, 0);
    stage(1, 32);
    __syncthreads();
    int cur = 0;
    for (int t = 0; t < nt; t += 2) {
      if (t + 2 < nt) {
        stage((cur ^ 1) * 2, (t + 2) * 32);
        stage((cur ^ 1) * 2 + 1, (t + 3) * 32);
      }
      compute(cur * 2);
      compute(cur * 2 + 1);
      __syncthreads();
      cur ^= 1;
    }
  }
  // loop ended with __syncthreads(): smem is reusable below.

  if constexpr (EPI == EPI_HALF_RES_T) {
    float* tr = (float*)smem;
#pragma unroll
    for (int i = 0; i < MI; ++i) {
      int rl0 = wm + i * 16 + g * 4;
#pragma unroll
      for (int j = 0; j < NI; ++j) {
        int cl = wn + j * 16 + c15;
        float bb = bias[n0 + cl];
#pragma unroll
        for (int r = 0; r < 4; ++r) {
          int row = m0 + rl0 + r;
          float v = resid[(size_t)row * N + n0 + cl] + 0.5f * (acc[i][j][r] + bb);
          tr[cl * 72 + rl0 + r] = v;
        }
      }
    }
    __syncthreads();
    const int bb = m0 >> 10, tt0 = m0 & 1023;
    const int c = tid >> 1, hf = tid & 1;
    float* dst = outF + ((size_t)bb * Dn + n0 + c) * Tn + tt0 + hf * 32;
    const float* srcp = tr + c * 72 + hf * 32;
#pragma unroll
    for (int k2 = 0; k2 < 8; ++k2)
      *(float4*)(dst + k2 * 4) = *(const float4*)(srcp + k2 * 4);
    return;
  }

  float gs_ = 0.0f, gq_ = 0.0f;
#pragma unroll
  for (int i = 0; i < MI; ++i) {
    int row0 = m0 + wm + i * 16 + g * 4;
#pragma unroll
    for (int j = 0; j < NI; ++j) {
      int col = n0 + wn + j * 16 + c15;
      int bcol = (EPI == EPI_GLU) ? ((col >> 1) + (col & 1) * 768) : col;
      float bb = bias[bcol];
#pragma unroll
      for (int r = 0; r < 4; ++r) {
        int row = row0 + r;
        float v = acc[i][j][r] + bb;
        if (EPI == EPI_GELU) {
          float inner = v + 0.044715f * v * v * v;
          v = v / (1.0f + ex2(inner * GEL_C));
        }
        else if (EPI == EPI_HALF_RES) v = resid[(size_t)row * N + col] + 0.5f * v;
        else if (EPI == EPI_RES) v = resid[(size_t)row * N + col] + v;
        if (EPI == EPI_GLU) {
          float partner = __shfl_xor(v, 1);
          if (!(c15 & 1))
            outF[(size_t)row * (N >> 1) + (col >> 1)] =
                v * (1.0f / (1.0f + ex2(-partner * L2E)));
        } else {
          size_t o = (size_t)row * N + col;
          if (outF) outF[o] = v;
          if (outB) outB[o] = __float2bfloat16(v);
          if (GNACC) { gs_ += v; gq_ += v * v; }
        }
      }
    }
  }

  if constexpr (GNACC) {
    // GN stats: wave reduce -> LDS -> 2 atomics per block (tile is in one batch b)
#pragma unroll
    for (int off = 1; off < 64; off <<= 1) {
      gs_ += __shfl_xor(gs_, off, 64);
      gq_ += __shfl_xor(gq_, off, 64);
    }
    float* red = (float*)smem;
    if (lane == 0) { red[wv] = gs_; red[4 + wv] = gq_; }
    __syncthreads();
    if (tid == 0) {
      float S = red[0] + red[1] + red[2] + red[3];
      float Q = red[4] + red[5] + red[6] + red[7];
      int b = m0 >> 10;
      atomicAdd(&gsum[b * 2], S);
      atomicAdd(&gsum[b * 2 + 1], Q);
    }
  }
}

// ---------------- attention (r17 kernel, known-good) ----------------
__global__ __launch_bounds__(256)
void k_attn(const __hip_bfloat16* __restrict__ qkv, const __hip_bfloat16* __restrict__ VT,
            const float* __restrict__ rel_tab,
            const float* __restrict__ gate_u, const float* __restrict__ gate_w,
            const float* __restrict__ gate_scale, __hip_bfloat16* __restrict__ ao) {
  __shared__ __align__(16) char smem[78336];
  __hip_bfloat16* qT = (__hip_bfloat16*)(smem + 60416);
  __hip_bfloat16* pT = (__hip_bfloat16*)(smem + 60416);
  float* relLocal = (float*)(smem + 73728);
  float* cRow = (float*)(smem + 78080);

  const int tid = threadIdx.x, lane = tid & 63, wv = tid >> 6;
  const int g = lane >> 4, c15 = lane & 15;
  const int orig = blockIdx.y * 16 + blockIdx.x;
  const int wg = (orig & 7) * 128 + (orig >> 3);
  const int qt = wg & 15;
  const int bh = wg >> 4;
  const int b = bh >> 3, h = bh & 7;
  const int t0 = qt * 64;

  const int kr_ = tid >> 2, kq4 = tid & 3;
  const __hip_bfloat16* kgbase =
      qkv + (size_t)(b * Tn + kr_) * 2304 + 768 + h * 96 + kq4 * 24;
  const int vrow0 = tid >> 3, vch = tid & 7;
  const int vrow1 = (256 + tid) >> 3, vrow2 = (512 + tid) >> 3;
  const __hip_bfloat16* vgbase = VT + (size_t)bh * 96 * Tn;

  for (int i = tid; i < 1087; i += 256)
    relLocal[i] = rel_tab[h * 2047 + i + 960 - t0];

  { // stage Q tile [64][96] -> qT stride 104
    const __hip_bfloat16* src = qkv + (size_t)(b * Tn + t0 + kr_) * 2304 + h * 96 + kq4 * 24;
    uint4 v0 = *(const uint4*)(src);
    uint4 v1 = *(const uint4*)(src + 8);
    uint4 v2 = *(const uint4*)(src + 16);
    *(uint4*)&qT[kr_ * 104 + kq4 * 24] = v0;
    *(uint4*)&qT[kr_ * 104 + kq4 * 24 + 8] = v1;
    *(uint4*)&qT[kr_ * 104 + kq4 * 24 + 16] = v2;
  }
  { // stage K/V tile 0 into kv[0] (prologue)
    __hip_bfloat16* kT0 = (__hip_bfloat16*)smem;
    __hip_bfloat16* vT0 = (__hip_bfloat16*)(smem + 13312);
    uint4 k0 = *(const uint4*)(kgbase);
    uint4 k1 = *(const uint4*)(kgbase + 8);
    uint4 k2 = *(const uint4*)(kgbase + 16);
    *(uint4*)&kT0[kr_ * 104 + kq4 * 24] = k0;
    *(uint4*)&kT0[kr_ * 104 + kq4 * 24 + 8] = k1;
    *(uint4*)&kT0[kr_ * 104 + kq4 * 24 + 16] = k2;
    uint4 w0 = *(const uint4*)(vgbase + (size_t)vrow0 * Tn + vch * 8);
    uint4 w1 = *(const uint4*)(vgbase + (size_t)vrow1 * Tn + vch * 8);
    uint4 w2 = *(const uint4*)(vgbase + (size_t)vrow2 * Tn + vch * 8);
    *(uint4*)&vT0[vrow0 * 88 + vch * 8] = w0;
    *(uint4*)&vT0[vrow1 * 88 + vch * 8] = w1;
    *(uint4*)&vT0[vrow2 * 88 + vch * 8] = w2;
  }
  __syncthreads();

  if (tid < 64) { // per-row gate scalar (exp2-domain: fold log2e)
    float du = 0.f, dw = 0.f;
#pragma unroll
    for (int c = 0; c < 12; ++c) {
      bf16x8 qv = *(const bf16x8*)&qT[tid * 104 + c * 8];
#pragma unroll
      for (int e = 0; e < 8; ++e) {
        float f = (float)qv[e];
        du += f * gate_u[h * 96 + c * 8 + e];
        dw += f * gate_w[h * 96 + c * 8 + e];
      }
    }
    float gu = 1.0f / (1.0f + __expf(-du));
    float gr = 1.0f / (1.0f + __expf(-dw));
    cRow[tid] = (1.0f + gu + (1.0f - gu) * gate_scale[h] * gr) * L2E;
  }

  bf16x8 aQ[3];
#pragma unroll
  for (int c = 0; c < 3; ++c)
    aQ[c] = *(const bf16x8*)&qT[(wv * 16 + c15) * 104 + c * 32 + g * 8];
  __syncthreads();

  float crw[4];
#pragma unroll
  for (int r = 0; r < 4; ++r) crw[r] = cRow[wv * 16 + g * 4 + r];

  float mrow[4], ssum[4];
#pragma unroll
  for (int r = 0; r < 4; ++r) { mrow[r] = -1e30f; ssum[r] = 0.0f; }
  f32x4 accO[6] = {};

  int cur = 0;
  for (int kt = 0; kt < 16; ++kt) {
    __hip_bfloat16* kT = (__hip_bfloat16*)(smem + cur * 30208);
    __hip_bfloat16* vT = (__hip_bfloat16*)(smem + cur * 30208 + 13312);

    uint4 nk0, nk1, nk2, nv0, nv1, nv2;
    if (kt < 15) {
      const __hip_bfloat16* kg = kgbase + (size_t)(kt + 1) * 64 * 2304;
      nk0 = *(const uint4*)(kg);
      nk1 = *(const uint4*)(kg + 8);
      nk2 = *(const uint4*)(kg + 16);
      const __hip_bfloat16* vg = vgbase + (kt + 1) * 64;
      nv0 = *(const uint4*)(vg + (size_t)vrow0 * Tn + vch * 8);
      nv1 = *(const uint4*)(vg + (size_t)vrow1 * Tn + vch * 8);
      nv2 = *(const uint4*)(vg + (size_t)vrow2 * Tn + vch * 8);
    }

    // S = Q K^T
    f32x4 accS[4];
    __builtin_amdgcn_s_setprio(1);
#pragma unroll
    for (int j = 0; j < 4; ++j) {
      f32x4 s = {};
#pragma unroll
      for (int c = 0; c < 3; ++c) {
        bf16x8 bk = *(const bf16x8*)&kT[(j * 16 + c15) * 104 + c * 32 + g * 8];
        s = __builtin_amdgcn_mfma_f32_16x16x32_bf16(aQ[c], bk, s, 0, 0, 0);
      }
      accS[j] = s;
    }
    __builtin_amdgcn_s_setprio(0);

    float sv[4][4];
    const int tq_off = wv * 16 + g * 4;
#pragma unroll
    for (int j = 0; j < 4; ++j) {
      int tk = kt * 64 + j * 16 + c15;
#pragma unroll
      for (int r = 0; r < 4; ++r)
        sv[j][r] = accS[j][r] * INV_SQRT_DH_L2E + crw[r] * relLocal[tk - (tq_off + r) + 63];
    }

    float lmax[4];
#pragma unroll
    for (int r = 0; r < 4; ++r)
      lmax[r] = fmaxf(fmaxf(sv[0][r], sv[1][r]), fmaxf(sv[2][r], sv[3][r]));
    int grow = (lmax[0] > mrow[0] + THR_L2E) | (lmax[1] > mrow[1] + THR_L2E) |
               (lmax[2] > mrow[2] + THR_L2E) | (lmax[3] > mrow[3] + THR_L2E);
    if (__any(grow)) {
#pragma unroll
      for (int r = 0; r < 4; ++r) {
        float m = lmax[r];
#pragma unroll
        for (int off = 1; off < 16; off <<= 1) m = fmaxf(m, __shfl_xor(m, off, 64));
        float newm = fmaxf(mrow[r], m);
        float sc = ex2(mrow[r] - newm);
        ssum[r] *= sc;
        mrow[r] = newm;
#pragma unroll
        for (int f = 0; f < 6; ++f) accO[f][r] *= sc;
      }
    }
#pragma unroll
    for (int r = 0; r < 4; ++r) {
      float ps = 0.0f;
#pragma unroll
      for (int j = 0; j < 4; ++j) {
        float p = ex2(sv[j][r] - mrow[r]);
        sv[j][r] = p;
        ps += p;
      }
      ssum[r] += ps;
    }

#pragma unroll
    for (int j = 0; j < 4; ++j)
#pragma unroll
      for (int r = 0; r < 4; ++r)
        pT[wv * 1408 + (g * 4 + r) * 88 + j * 16 + c15] = __float2bfloat16(sv[j][r]);

    bf16x8 ap0 = *(const bf16x8*)&pT[wv * 1408 + c15 * 88 + g * 8];
    bf16x8 ap1 = *(const bf16x8*)&pT[wv * 1408 + c15 * 88 + 32 + g * 8];
    __builtin_amdgcn_s_setprio(1);
#pragma unroll
    for (int f = 0; f < 6; ++f) {
      bf16x8 bv0 = *(const bf16x8*)&vT[(f * 16 + c15) * 88 + g * 8];
      bf16x8 bv1 = *(const bf16x8*)&vT[(f * 16 + c15) * 88 + 32 + g * 8];
      accO[f] = __builtin_amdgcn_mfma_f32_16x16x32_bf16(ap0, bv0, accO[f], 0, 0, 0);
      accO[f] = __builtin_amdgcn_mfma_f32_16x16x32_bf16(ap1, bv1, accO[f], 0, 0, 0);
    }
    __builtin_amdgcn_s_setprio(0);

    if (kt < 15) {
      __hip_bfloat16* kTn = (__hip_bfloat16*)(smem + (cur ^ 1) * 30208);
      __hip_bfloat16* vTn = (__hip_bfloat16*)(smem + (cur ^ 1) * 30208 + 13312);
      *(uint4*)&kTn[kr_ * 104 + kq4 * 24] = nk0;
      *(uint4*)&kTn[kr_ * 104 + kq4 * 24 + 8] = nk1;
      *(uint4*)&kTn[kr_ * 104 + kq4 * 24 + 16] = nk2;
      *(uint4*)&vTn[vrow0 * 88 + vch * 8] = nv0;
      *(uint4*)&vTn[vrow1 * 88 + vch * 8] = nv1;
      *(uint4*)&vTn[vrow2 * 88 + vch * 8] = nv2;
    }
    __syncthreads();
    cur ^= 1;
  }

  float inv[4];
#pragma unroll
  for (int r = 0; r < 4; ++r) {
    float s = ssum[r];
#pragma unroll
    for (int off = 1; off < 16; off <<= 1) s += __shfl_xor(s, off, 64);
    inv[r] = 1.0f / s;
  }
#pragma unroll
  for (int f = 0; f < 6; ++f)
#pragma unroll
    for (int r = 0; r < 4; ++r) {
      int trow = t0 + wv * 16 + g * 4 + r;
      ao[(size_t)(b * Tn + trow) * Dn + h * 96 + f * 16 + c15] =
          __float2bfloat16(accO[f][r] * inv[r]);
    }
}

// ---------------- depthwise conv K=31 (+ fused GN2 partial stats) ----------------
__global__ __launch_bounds__(256)
void k_dwconv(const float* __restrict__ in, const float* __restrict__ w,
              const float* __restrict__ bias, float* __restrict__ out,
              float* __restrict__ gsum) {
  __shared__ float tile[94][64];
  __shared__ float wt[64][31];
  __shared__ float bt[64];
  __shared__ float rs[4], rq[4];
  int b = blockIdx.z, t0 = blockIdx.x * 64, d0 = blockIdx.y * 64;
  int tid = threadIdx.x;
  for (int e = tid; e < 94 * 64; e += 256) {
    int rr = e >> 6, dd = e & 63;
    int t = t0 - 15 + rr;
    tile[rr][dd] = (t >= 0 && t < Tn) ? in[(size_t)(b * Tn + t) * Dn + d0 + dd] : 0.0f;
  }
  for (int e = tid; e < 64 * 31; e += 256) {
    int dd = e / 31, k = e - dd * 31;
    wt[dd][k] = w[(d0 + dd) * 31 + k];
  }
  if (tid < 64) bt[tid] = bias[d0 + tid];
  __syncthreads();
  float gs_ = 0.0f, gq_ = 0.0f;
  for (int o = tid; o < 64 * 64; o += 256) {
    int tt = o >> 6, dd = o & 63;
    float s = bt[dd];
#pragma unroll
    for (int k = 0; k < 31; ++k) s += tile[tt + k][dd] * wt[dd][k];
    out[(size_t)(b * Tn + t0 + tt) * Dn + d0 + dd] = s;
    gs_ += s; gq_ += s * s;
  }
  int lane = tid & 63, wv = tid >> 6;
#pragma unroll
  for (int off = 1; off < 64; off <<= 1) {
    gs_ += __shfl_xor(gs_, off, 64);
    gq_ += __shfl_xor(gq_, off, 64);
  }
  if (lane == 0) { rs[wv] = gs_; rq[wv] = gq_; }
  __syncthreads();
  if (tid == 0) {
    atomicAdd(&gsum[b * 2], rs[0] + rs[1] + rs[2] + rs[3]);
    atomicAdd(&gsum[b * 2 + 1], rq[0] + rq[1] + rq[2] + rq[3]);
  }
}

// ---------------- GN stats finalize (from fused sums) ----------------
__global__ void k_gn_final2(const float* __restrict__ gs, float* __restrict__ stats) {
  int b = threadIdx.x;
  if (b < 8) {
    const float N = (float)(Dn * Tn);
    float mean = gs[b * 2] / N;
    float var = gs[b * 2 + 1] / N - mean * mean;
    stats[b * 2] = mean;
    stats[b * 2 + 1] = rsqrtf(var + 1e-5f);
  }
}

// vectorized: 4 elems/thread
template <bool SILU>
__global__ void k_gn_apply(const float* __restrict__ x, const float* __restrict__ stats,
                           const float* __restrict__ w, const float* __restrict__ bb,
                           __hip_bfloat16* __restrict__ out) {
  int i4 = (blockIdx.x * 256 + threadIdx.x) * 4;
  if (i4 >= BT * Dn) return;
  int row = i4 / Dn, d = i4 - row * Dn;
  int b = row >> 10;
  float mean = stats[b * 2], rstd = stats[b * 2 + 1];
  float4 xv = *(const float4*)(x + i4);
  float4 wv4 = *(const float4*)(w + d);
  float4 bv4 = *(const float4*)(bb + d);
  float v0 = (xv.x - mean) * rstd * wv4.x + bv4.x;
  float v1 = (xv.y - mean) * rstd * wv4.y + bv4.y;
  float v2 = (xv.z - mean) * rstd * wv4.z + bv4.z;
  float v3 = (xv.w - mean) * rstd * wv4.w + bv4.w;
  if (SILU) {
    v0 = v0 / (1.0f + ex2(-v0 * L2E));
    v1 = v1 / (1.0f + ex2(-v1 * L2E));
    v2 = v2 / (1.0f + ex2(-v2 * L2E));
    v3 = v3 / (1.0f + ex2(-v3 * L2E));
  }
  union { ushort4 u; __hip_bfloat16 h[4]; } o;
  o.h[0] = __float2bfloat16(v0);
  o.h[1] = __float2bfloat16(v1);
  o.h[2] = __float2bfloat16(v2);
  o.h[3] = __float2bfloat16(v3);
  *(ushort4*)(out + i4) = o.u;
}

// ---------------- launch ----------------
extern "C" void kernel_launch(void* const* d_in, const int* in_sizes, int n_in,
                              void* d_out, int out_size, void* d_ws, size_t ws_size,
                              hipStream_t stream) {
  const float* x         = (const float*)d_in[0];
  const float* w_ff1a    = (const float*)d_in[1];
  const float* b_ff1a    = (const float*)d_in[2];
  const float* w_ff1b    = (const float*)d_in[3];
  const float* b_ff1b    = (const float*)d_in[4];
  const float* w_qkv     = (const float*)d_in[5];
  const float* b_qkv     = (const float*)d_in[6];
  const float* w_out     = (const float*)d_in[7];
  const float* b_out     = (const float*)d_in[8];
  const float* rel_embed = (const float*)d_in[9];
  const float* gate_u    = (const float*)d_in[10];
  const float* gate_w    = (const float*)d_in[11];
  const float* gate_sc   = (const float*)d_in[12];
  const float* gn1_w     = (const float*)d_in[13];
  const float* gn1_b     = (const float*)d_in[14];
  const float* pw1_w     = (const float*)d_in[15];
  const float* pw1_b     = (const float*)d_in[16];
  const float* dw_w      = (const float*)d_in[17];
  const float* dw_b      = (const float*)d_in[18];
  const float* gn2_w     = (const float*)d_in[19];
  const float* gn2_b     = (const float*)d_in[20];
  const float* pw2_w     = (const float*)d_in[21];
  const float* pw2_b     = (const float*)d_in[22];
  const float* w_ff2a    = (const float*)d_in[23];
  const float* b_ff2a    = (const float*)d_in[24];
  const float* w_ff2b    = (const float*)d_in[25];
  const float* b_ff2b    = (const float*)d_in[26];

  char* ws = (char*)d_ws;
  size_t off = 0;
  auto alloc = [&](size_t bytes) {
    void* p = ws + off;
    off = (off + bytes + 255) & ~(size_t)255;
    return p;
  };

  float* SA = (float*)alloc((size_t)BT * Dn * 4);
  float* SB = (float*)alloc((size_t)BT * Dn * 4);
  __hip_bfloat16* ABF = (__hip_bfloat16*)alloc((size_t)BT * Dn * 2);
  void* BIG = alloc((size_t)BT * FFn * 2);
  void* QKV = alloc((size_t)BT * 2304 * 2);
  __hip_bfloat16* Wf1a = (__hip_bfloat16*)alloc((size_t)Dn * FFn * 2);
  __hip_bfloat16* Wf1b = (__hip_bfloat16*)alloc((size_t)Dn * FFn * 2);
  __hip_bfloat16* Wqkv = (__hip_bfloat16*)alloc((size_t)Dn * 2304 * 2);
  __hip_bfloat16* Wout = (__hip_bfloat16*)alloc((size_t)Dn * Dn * 2);
  __hip_bfloat16* Wpw1 = (__hip_bfloat16*)alloc((size_t)1536 * Dn * 2);
  __hip_bfloat16* Wpw2 = (__hip_bfloat16*)alloc((size_t)Dn * Dn * 2);
  __hip_bfloat16* Wf2a = (__hip_bfloat16*)alloc((size_t)Dn * FFn * 2);
  __hip_bfloat16* Wf2b = (__hip_bfloat16*)alloc((size_t)Dn * FFn * 2);
  float* RELT  = (float*)alloc(8 * 2047 * 4);
  float* GS1   = (float*)alloc(16 * 4);
  float* GS2   = (float*)alloc(16 * 4);
  float* GSTAT = (float*)alloc(8 * 2 * 4);
  __hip_bfloat16* VT = (__hip_bfloat16*)BIG;
  float* GLUF = (float*)QKV;                       // fp32 overlay (pw1->dwconv)
  __hip_bfloat16* ABF2 = (__hip_bfloat16*)QKV;     // bf16 overlay (pw2 out)
  float* DWO = (float*)d_out;                      // dwconv scratch; overwritten by FF2b-T

  dim3 blk32(32, 8);

  const int PREP_BLOCKS = 2304 + 2304 + 1728 + 576 + 2304 + 2304 + 1152 + 576 + 8;
  k_prep<<<PREP_BLOCKS, 256, 0, stream>>>(
      w_ff1a, w_ff1b, w_qkv, w_out, w_ff2a, w_ff2b, pw1_w, pw2_w, rel_embed,
      Wf1a, Wf1b, Wqkv, Wout, Wf2a, Wf2b, Wpw1, Wpw2, RELT, GS1, GS2);

  k_tin<<<dim3(Tn / 32, Dn / 32, Bn), blk32, 0, stream>>>(x, SA, ABF);

  // FF1
  k_gemm<128, 128, 1, EPI_GELU, false><<<dim3(FFn / 128, BT / 128), 256, 0, stream>>>(
      ABF, Wf1a, b_ff1a, nullptr, nullptr, (__hip_bfloat16*)BIG, nullptr, BT, FFn, Dn);
  k_gemm<64, 128, 2, EPI_HALF_RES, false><<<dim3(Dn / 128, BT / 64), 256, 0, stream>>>(
      (__hip_bfloat16*)BIG, Wf1b, b_ff1b, SA, SB, ABF, nullptr, BT, Dn, FFn);

  // QKV
  k_gemm<128, 128, 1, EPI_BIAS, false><<<dim3(2304 / 128, BT / 128), 256, 0, stream>>>(
      ABF, Wqkv, b_qkv, nullptr, nullptr, (__hip_bfloat16*)QKV, nullptr, BT, 2304, Dn);

  // V pre-transpose
  k_vtrans<<<dim3(Tn / 32, 3, 64), blk32, 0, stream>>>((const __hip_bfloat16*)QKV, VT);

  // attention -> ABF (bf16)
  k_attn<<<dim3(16, 64), 256, 0, stream>>>((const __hip_bfloat16*)QKV, VT, RELT,
                                           gate_u, gate_w, gate_sc, ABF);

  // out-proj + residual(SB) -> SA, fused GN1 partial stats -> GS1
  k_gemm<64, 128, 2, EPI_RES, true><<<dim3(Dn / 128, BT / 64), 256, 0, stream>>>(
      ABF, Wout, b_out, SB, SA, nullptr, GS1, BT, Dn, Dn);

  // GN1 finalize + apply
  k_gn_final2<<<1, 8, 0, stream>>>(GS1, GSTAT);
  k_gn_apply<false><<<(BT * Dn / 4 + 255) / 256, 256, 0, stream>>>(SA, GSTAT, gn1_w, gn1_b, ABF);

  // pw1 + fused GLU -> GLUF fp32 [BT][768]
  k_gemm<64, 128, 2, EPI_GLU, false><<<dim3(1536 / 128, BT / 64), 256, 0, stream>>>(
      ABF, Wpw1, pw1_b, nullptr, GLUF, nullptr, nullptr, BT, 1536, Dn);
  // dwconv -> DWO, fused GN2 partial stats -> GS2
  k_dwconv<<<dim3(Tn / 64, Dn / 64, Bn), 256, 0, stream>>>(GLUF, dw_w, dw_b, DWO, GS2);
  // GN2 finalize + apply(SiLU)
  k_gn_final2<<<1, 8, 0, stream>>>(GS2, GSTAT);
  k_gn_apply<true><<<(BT * Dn / 4 + 255) / 256, 256, 0, stream>>>(DWO, GSTAT, gn2_w, gn2_b, ABF);

  // pw2 + residual(SA) -> SB fp32 + ABF2 bf16 (no in-place ABF write: race)
  k_gemm<64, 128, 2, EPI_RES, false><<<dim3(Dn / 128, BT / 64), 256, 0, stream>>>(
      ABF, Wpw2, pw2_b, SA, SB, ABF2, nullptr, BT, Dn, Dn);

  // FF2 (reads ABF2); FF2b writes d_out directly (transposed epilogue)
  k_gemm<128, 128, 1, EPI_GELU, false><<<dim3(FFn / 128, BT / 128), 256, 0, stream>>>(
      ABF2, Wf2a, b_ff2a, nullptr, nullptr, (__hip_bfloat16*)BIG, nullptr, BT, FFn, Dn);
  k_gemm<64, 128, 2, EPI_HALF_RES_T, false><<<dim3(Dn / 128, BT / 64), 256, 0, stream>>>(
      (__hip_bfloat16*)BIG, Wf2b, b_ff2b, SB, (float*)d_out, nullptr, nullptr, BT, Dn, FFn);
}

// Round 21
// 546.821 us; speedup vs baseline: 1.0517x; 1.0517x over previous
//
#include <hip/hip_runtime.h>
#include <hip/hip_bf16.h>
#include <cstdint>

typedef __attribute__((ext_vector_type(8))) __bf16 bf16x8;
typedef __attribute__((ext_vector_type(4))) float f32x4;
typedef unsigned short u16t;

constexpr int Bn = 8, Dn = 768, Tn = 1024, Hn = 8, DHn = 96, FFn = 3072;
constexpr int BT = Bn * Tn; // 8192
constexpr float INV_SQRT_DH_L2E = 0.14724444927f; // (1/sqrt(96)) * log2(e)
constexpr float L2E = 1.4426950408889634f;
constexpr float THR_L2E = 11.541560327f;          // 8 * log2(e)
constexpr float GEL_C = -2.0f * 0.7978845608f * L2E; // -2*sqrt(2/pi)*log2(e)

#define GLDS16(gp, lp) __builtin_amdgcn_global_load_lds( \
    (__attribute__((address_space(1))) unsigned int*)(uintptr_t)(gp), \
    (__attribute__((address_space(3))) unsigned int*)(uintptr_t)(lp), 16, 0, 0)

// bare v_exp_f32 (2^x). underflow->0, overflow->inf; both give correct sigmoid limits.
__device__ __forceinline__ float ex2(float x) {
  float r;
  asm("v_exp_f32 %0, %1" : "=v"(r) : "v"(x));
  return r;
}

// ---------------- merged weight prep (one launch) ----------------
__global__ void k_prep(const float* __restrict__ w_ff1a, const float* __restrict__ w_ff1b,
                       const float* __restrict__ w_qkv, const float* __restrict__ w_out,
                       const float* __restrict__ w_ff2a, const float* __restrict__ w_ff2b,
                       const float* __restrict__ pw1_w, const float* __restrict__ pw2_w,
                       const float* __restrict__ rel_embed,
                       __hip_bfloat16* __restrict__ Wf1a, __hip_bfloat16* __restrict__ Wf1b,
                       __hip_bfloat16* __restrict__ Wqkv, __hip_bfloat16* __restrict__ Wout,
                       __hip_bfloat16* __restrict__ Wf2a, __hip_bfloat16* __restrict__ Wf2b,
                       __hip_bfloat16* __restrict__ Wpw1, __hip_bfloat16* __restrict__ Wpw2,
                       float* __restrict__ rel_tab) {
  __shared__ float t[32][33];
  const int tid = threadIdx.x;
  int bid = blockIdx.x;

  const float* tsrc = nullptr;
  __hip_bfloat16* tdst = nullptr;
  int K = 0, N = 0;
  if (bid < 2304) { tsrc = w_ff1a; tdst = Wf1a; K = 768; N = 3072; }
  else if ((bid -= 2304) < 2304) { tsrc = w_ff1b; tdst = Wf1b; K = 3072; N = 768; }
  else if ((bid -= 2304) < 1728) { tsrc = w_qkv; tdst = Wqkv; K = 768; N = 2304; }
  else if ((bid -= 1728) < 576)  { tsrc = w_out; tdst = Wout; K = 768; N = 768; }
  else if ((bid -= 576) < 2304)  { tsrc = w_ff2a; tdst = Wf2a; K = 768; N = 3072; }
  else if ((bid -= 2304) < 2304) { tsrc = w_ff2b; tdst = Wf2b; K = 3072; N = 768; }
  else {
    bid -= 2304;
    if (bid < 1152) { // pw1 interleave
      int i4 = bid * 1024 + tid * 4;
      int n = i4 / 768, k = i4 - n * 768;
      int on = (n >> 1) + (n & 1) * 768;
      float4 v = *(const float4*)(pw1_w + (size_t)on * 768 + k);
      __hip_bfloat16* d = Wpw1 + i4;
      d[0] = __float2bfloat16(v.x); d[1] = __float2bfloat16(v.y);
      d[2] = __float2bfloat16(v.z); d[3] = __float2bfloat16(v.w);
    } else if ((bid -= 1152) < 576) { // pw2 convert
      int i4 = bid * 1024 + tid * 4;
      float4 v = *(const float4*)(pw2_w + i4);
      __hip_bfloat16* d = Wpw2 + i4;
      d[0] = __float2bfloat16(v.x); d[1] = __float2bfloat16(v.y);
      d[2] = __float2bfloat16(v.z); d[3] = __float2bfloat16(v.w);
    } else { // rel table
      bid -= 576;
      int dd = bid * 256 + tid;
      if (dd < 2047) {
        int d = dd - 1023;
        int sign = d >= 0 ? 1 : 0;
        int ra = d < 0 ? -d : d;
        int base;
        if (ra < 80) base = ra;
        else {
          float lr = logf((float)ra / 80.0f) / 2.3025851f;
          int lp = 80 + (int)(lr * 80.0f);
          base = lp < 159 ? lp : 159;
        }
        int bucket = base + sign * 160;
        if (bucket < 0) bucket = 0;
        if (bucket > 319) bucket = 319;
        for (int h = 0; h < 8; ++h)
          rel_tab[h * 2047 + dd] = rel_embed[bucket * 8 + h];
      }
    }
    return;
  }
  int nb32 = N / 32;
  int nb = (bid % nb32) * 32, kb = (bid / nb32) * 32;
  int tx = tid & 31, ty = tid >> 5;
  for (int i = ty; i < 32; i += 8)
    t[i][tx] = tsrc[(size_t)(kb + i) * N + nb + tx];
  __syncthreads();
  for (int i = ty; i < 32; i += 8)
    tdst[(size_t)(nb + i) * K + kb + tx] = __float2bfloat16(t[tx][i]);
}

// ---------------- transposes ----------------
__global__ void k_tin(const float* __restrict__ x, float* __restrict__ s,
                      __hip_bfloat16* __restrict__ sb) {
  __shared__ float t[32][33];
  int b = blockIdx.z;
  int t0 = blockIdx.x * 32, d0 = blockIdx.y * 32;
  int tx = threadIdx.x, ty = threadIdx.y;
  for (int i = ty; i < 32; i += 8)
    t[i][tx] = x[((size_t)b * Dn + d0 + i) * Tn + t0 + tx];
  __syncthreads();
  for (int i = ty; i < 32; i += 8) {
    float v = t[tx][i];
    size_t o = (size_t)(b * Tn + t0 + i) * Dn + d0 + tx;
    s[o] = v;
    sb[o] = __float2bfloat16(v);
  }
}

// V part of qkv -> VT[(b*8+h)*96 + d][1024]
__global__ void k_vtrans(const __hip_bfloat16* __restrict__ qkv,
                         __hip_bfloat16* __restrict__ VT) {
  __shared__ __hip_bfloat16 t[32][33];
  int bh = blockIdx.z;
  int b = bh >> 3, h = bh & 7;
  int t0 = blockIdx.x * 32, d0 = blockIdx.y * 32;
  int tx = threadIdx.x, ty = threadIdx.y;
  for (int i = ty; i < 32; i += 8)
    t[i][tx] = qkv[(size_t)(b * Tn + t0 + i) * 2304 + 1536 + h * 96 + d0 + tx];
  __syncthreads();
  for (int i = ty; i < 32; i += 8)
    VT[((size_t)bh * 96 + d0 + i) * Tn + t0 + tx] = t[tx][i];
}

// ---------------- GEMM: C = A[M,K] * Bt[N,K]^T, bf16 in, fp32 acc ----------------
// EPI_HALF_RES_T: resid + 0.5v, then transpose via LDS and write outF as
// d_out[B][D][T] directly (fuses the final k_tout).
enum { EPI_BIAS = 0, EPI_GELU = 1, EPI_HALF_RES = 2, EPI_RES = 3, EPI_GLU = 4,
       EPI_HALF_RES_T = 5 };

template <int BM, int BN, int DEPTH, int EPI>
__global__ __launch_bounds__(256)
void k_gemm(const __hip_bfloat16* __restrict__ A, const __hip_bfloat16* __restrict__ Bt,
            const float* __restrict__ bias, const float* __restrict__ resid,
            float* __restrict__ outF, __hip_bfloat16* __restrict__ outB,
            int M, int N, int K) {
  constexpr int MI = BM / 32;
  constexpr int NI = BN / 32;
  constexpr int ASZ = BM * 32;                 // bf16 elems per A buffer
  constexpr int BSZ = BN * 32;
  constexpr int STG_BYTES = 2 * DEPTH * (ASZ + BSZ) * 2;
  constexpr int TR_BYTES = (EPI == EPI_HALF_RES_T) ? BN * 72 * 4 : 0;
  constexpr int SMEM_BYTES = (TR_BYTES > STG_BYTES) ? TR_BYTES : STG_BYTES;
  __shared__ __align__(16) char smem[SMEM_BYTES];
  __hip_bfloat16* lAp = (__hip_bfloat16*)smem;
  __hip_bfloat16* lBp = (__hip_bfloat16*)(smem + (size_t)2 * DEPTH * ASZ * 2);

  const int tid = threadIdx.x;
  const int lane = tid & 63, wv = tid >> 6;
  const int g = lane >> 4, c15 = lane & 15;
  const int gx = gridDim.x;
  const int nwg = gx * gridDim.y;
  const int orig = blockIdx.y * gx + blockIdx.x;
  const int q = nwg >> 3, rr = nwg & 7;
  const int xcd = orig & 7, idx = orig >> 3;
  const int wg = (xcd < rr ? xcd * (q + 1) : rr * (q + 1) + (xcd - rr) * q) + idx;
  const int m0 = (wg / gx) * BM, n0 = (wg % gx) * BN;
  const int wm = (wv >> 1) * (BM / 2), wn = (wv & 1) * (BN / 2);

  const int srow = lane >> 2, scol = (lane & 3) * 8;

  f32x4 acc[MI][NI] = {};

  auto stage = [&](int buf, int kt) {
#pragma unroll
    for (int c = 0; c < BM / 64; ++c) {
      int cid = wv * (BM / 64) + c;
      GLDS16(A + (size_t)(m0 + cid * 16 + srow) * K + kt + scol, lAp + buf * ASZ + cid * 512);
    }
#pragma unroll
    for (int c = 0; c < BN / 64; ++c) {
      int cid = wv * (BN / 64) + c;
      GLDS16(Bt + (size_t)(n0 + cid * 16 + srow) * K + kt + scol, lBp + buf * BSZ + cid * 512);
    }
  };

  auto compute = [&](int buf) {
    bf16x8 af[MI], bfr[NI];
#pragma unroll
    for (int i = 0; i < MI; ++i)
      af[i] = *(const bf16x8*)&lAp[buf * ASZ + (wm + i * 16 + c15) * 32 + g * 8];
#pragma unroll
    for (int j = 0; j < NI; ++j)
      bfr[j] = *(const bf16x8*)&lBp[buf * BSZ + (wn + j * 16 + c15) * 32 + g * 8];
#pragma unroll
    for (int i = 0; i < MI; ++i)
#pragma unroll
      for (int j = 0; j < NI; ++j)
        acc[i][j] = __builtin_amdgcn_mfma_f32_16x16x32_bf16(af[i], bfr[j], acc[i][j], 0, 0, 0);
  };

  const int nt = K >> 5;
  if constexpr (DEPTH == 1) {
    stage(0, 0);
    __syncthreads();
    int cur = 0;
    for (int t = 0; t < nt; ++t) {
      if (t + 1 < nt) stage(cur ^ 1, (t + 1) * 32);
      compute(cur);
      __syncthreads();
      cur ^= 1;
    }
  } else {
    stage(0, 0);
    stage(1, 32);
    __syncthreads();
    int cur = 0;
    for (int t = 0; t < nt; t += 2) {
      if (t + 2 < nt) {
        stage((cur ^ 1) * 2, (t + 2) * 32);
        stage((cur ^ 1) * 2 + 1, (t + 3) * 32);
      }
      compute(cur * 2);
      compute(cur * 2 + 1);
      __syncthreads();
      cur ^= 1;
    }
  }
  // loop ended with __syncthreads(): smem is reusable below.

  if constexpr (EPI == EPI_HALF_RES_T) {
    float* tr = (float*)smem;
#pragma unroll
    for (int i = 0; i < MI; ++i) {
      int rl0 = wm + i * 16 + g * 4;
#pragma unroll
      for (int j = 0; j < NI; ++j) {
        int cl = wn + j * 16 + c15;
        float bb = bias[n0 + cl];
#pragma unroll
        for (int r = 0; r < 4; ++r) {
          int row = m0 + rl0 + r;
          float v = resid[(size_t)row * N + n0 + cl] + 0.5f * (acc[i][j][r] + bb);
          tr[cl * 72 + rl0 + r] = v;
        }
      }
    }
    __syncthreads();
    // coalesced write to d_out [B][D][T]; BM=64 divides Tn so tile is in one b.
    const int bb = m0 >> 10, tt0 = m0 & 1023;
    const int c = tid >> 1, hf = tid & 1;
    float* dst = outF + ((size_t)bb * Dn + n0 + c) * Tn + tt0 + hf * 32;
    const float* srcp = tr + c * 72 + hf * 32;
#pragma unroll
    for (int k2 = 0; k2 < 8; ++k2)
      *(float4*)(dst + k2 * 4) = *(const float4*)(srcp + k2 * 4);
    return;
  }

#pragma unroll
  for (int i = 0; i < MI; ++i) {
    int row0 = m0 + wm + i * 16 + g * 4;
#pragma unroll
    for (int j = 0; j < NI; ++j) {
      int col = n0 + wn + j * 16 + c15;
      int bcol = (EPI == EPI_GLU) ? ((col >> 1) + (col & 1) * 768) : col;
      float bb = bias[bcol];
#pragma unroll
      for (int r = 0; r < 4; ++r) {
        int row = row0 + r;
        float v = acc[i][j][r] + bb;
        if (EPI == EPI_GELU) {
          float inner = v + 0.044715f * v * v * v;
          v = v / (1.0f + ex2(inner * GEL_C));
        }
        else if (EPI == EPI_HALF_RES) v = resid[(size_t)row * N + col] + 0.5f * v;
        else if (EPI == EPI_RES) v = resid[(size_t)row * N + col] + v;
        if (EPI == EPI_GLU) {
          float partner = __shfl_xor(v, 1);
          if (!(c15 & 1))
            outF[(size_t)row * (N >> 1) + (col >> 1)] =
                v * (1.0f / (1.0f + ex2(-partner * L2E)));
        } else {
          size_t o = (size_t)row * N + col;
          if (outF) outF[o] = v;
          if (outB) outB[o] = __float2bfloat16(v);
        }
      }
    }
  }
}

// ---------------- attention (r17 kernel, known-good) ----------------
__global__ __launch_bounds__(256)
void k_attn(const __hip_bfloat16* __restrict__ qkv, const __hip_bfloat16* __restrict__ VT,
            const float* __restrict__ rel_tab,
            const float* __restrict__ gate_u, const float* __restrict__ gate_w,
            const float* __restrict__ gate_scale, __hip_bfloat16* __restrict__ ao) {
  __shared__ __align__(16) char smem[78336];
  __hip_bfloat16* qT = (__hip_bfloat16*)(smem + 60416);
  __hip_bfloat16* pT = (__hip_bfloat16*)(smem + 60416);
  float* relLocal = (float*)(smem + 73728);
  float* cRow = (float*)(smem + 78080);

  const int tid = threadIdx.x, lane = tid & 63, wv = tid >> 6;
  const int g = lane >> 4, c15 = lane & 15;
  const int orig = blockIdx.y * 16 + blockIdx.x;
  const int wg = (orig & 7) * 128 + (orig >> 3);
  const int qt = wg & 15;
  const int bh = wg >> 4;
  const int b = bh >> 3, h = bh & 7;
  const int t0 = qt * 64;

  const int kr_ = tid >> 2, kq4 = tid & 3;
  const __hip_bfloat16* kgbase =
      qkv + (size_t)(b * Tn + kr_) * 2304 + 768 + h * 96 + kq4 * 24;
  const int vrow0 = tid >> 3, vch = tid & 7;
  const int vrow1 = (256 + tid) >> 3, vrow2 = (512 + tid) >> 3;
  const __hip_bfloat16* vgbase = VT + (size_t)bh * 96 * Tn;

  for (int i = tid; i < 1087; i += 256)
    relLocal[i] = rel_tab[h * 2047 + i + 960 - t0];

  { // stage Q tile [64][96] -> qT stride 104
    const __hip_bfloat16* src = qkv + (size_t)(b * Tn + t0 + kr_) * 2304 + h * 96 + kq4 * 24;
    uint4 v0 = *(const uint4*)(src);
    uint4 v1 = *(const uint4*)(src + 8);
    uint4 v2 = *(const uint4*)(src + 16);
    *(uint4*)&qT[kr_ * 104 + kq4 * 24] = v0;
    *(uint4*)&qT[kr_ * 104 + kq4 * 24 + 8] = v1;
    *(uint4*)&qT[kr_ * 104 + kq4 * 24 + 16] = v2;
  }
  { // stage K/V tile 0 into kv[0] (prologue)
    __hip_bfloat16* kT0 = (__hip_bfloat16*)smem;
    __hip_bfloat16* vT0 = (__hip_bfloat16*)(smem + 13312);
    uint4 k0 = *(const uint4*)(kgbase);
    uint4 k1 = *(const uint4*)(kgbase + 8);
    uint4 k2 = *(const uint4*)(kgbase + 16);
    *(uint4*)&kT0[kr_ * 104 + kq4 * 24] = k0;
    *(uint4*)&kT0[kr_ * 104 + kq4 * 24 + 8] = k1;
    *(uint4*)&kT0[kr_ * 104 + kq4 * 24 + 16] = k2;
    uint4 w0 = *(const uint4*)(vgbase + (size_t)vrow0 * Tn + vch * 8);
    uint4 w1 = *(const uint4*)(vgbase + (size_t)vrow1 * Tn + vch * 8);
    uint4 w2 = *(const uint4*)(vgbase + (size_t)vrow2 * Tn + vch * 8);
    *(uint4*)&vT0[vrow0 * 88 + vch * 8] = w0;
    *(uint4*)&vT0[vrow1 * 88 + vch * 8] = w1;
    *(uint4*)&vT0[vrow2 * 88 + vch * 8] = w2;
  }
  __syncthreads();

  if (tid < 64) { // per-row gate scalar (exp2-domain: fold log2e)
    float du = 0.f, dw = 0.f;
#pragma unroll
    for (int c = 0; c < 12; ++c) {
      bf16x8 qv = *(const bf16x8*)&qT[tid * 104 + c * 8];
#pragma unroll
      for (int e = 0; e < 8; ++e) {
        float f = (float)qv[e];
        du += f * gate_u[h * 96 + c * 8 + e];
        dw += f * gate_w[h * 96 + c * 8 + e];
      }
    }
    float gu = 1.0f / (1.0f + __expf(-du));
    float gr = 1.0f / (1.0f + __expf(-dw));
    cRow[tid] = (1.0f + gu + (1.0f - gu) * gate_scale[h] * gr) * L2E;
  }

  bf16x8 aQ[3];
#pragma unroll
  for (int c = 0; c < 3; ++c)
    aQ[c] = *(const bf16x8*)&qT[(wv * 16 + c15) * 104 + c * 32 + g * 8];
  __syncthreads();

  float crw[4];
#pragma unroll
  for (int r = 0; r < 4; ++r) crw[r] = cRow[wv * 16 + g * 4 + r];

  float mrow[4], ssum[4];
#pragma unroll
  for (int r = 0; r < 4; ++r) { mrow[r] = -1e30f; ssum[r] = 0.0f; }
  f32x4 accO[6] = {};

  int cur = 0;
  for (int kt = 0; kt < 16; ++kt) {
    __hip_bfloat16* kT = (__hip_bfloat16*)(smem + cur * 30208);
    __hip_bfloat16* vT = (__hip_bfloat16*)(smem + cur * 30208 + 13312);

    uint4 nk0, nk1, nk2, nv0, nv1, nv2;
    if (kt < 15) {
      const __hip_bfloat16* kg = kgbase + (size_t)(kt + 1) * 64 * 2304;
      nk0 = *(const uint4*)(kg);
      nk1 = *(const uint4*)(kg + 8);
      nk2 = *(const uint4*)(kg + 16);
      const __hip_bfloat16* vg = vgbase + (kt + 1) * 64;
      nv0 = *(const uint4*)(vg + (size_t)vrow0 * Tn + vch * 8);
      nv1 = *(const uint4*)(vg + (size_t)vrow1 * Tn + vch * 8);
      nv2 = *(const uint4*)(vg + (size_t)vrow2 * Tn + vch * 8);
    }

    // S = Q K^T
    f32x4 accS[4];
    __builtin_amdgcn_s_setprio(1);
#pragma unroll
    for (int j = 0; j < 4; ++j) {
      f32x4 s = {};
#pragma unroll
      for (int c = 0; c < 3; ++c) {
        bf16x8 bk = *(const bf16x8*)&kT[(j * 16 + c15) * 104 + c * 32 + g * 8];
        s = __builtin_amdgcn_mfma_f32_16x16x32_bf16(aQ[c], bk, s, 0, 0, 0);
      }
      accS[j] = s;
    }
    __builtin_amdgcn_s_setprio(0);

    // scores in exp2-domain (log2e folded into both coefficients)
    float sv[4][4];
    const int tq_off = wv * 16 + g * 4;
#pragma unroll
    for (int j = 0; j < 4; ++j) {
      int tk = kt * 64 + j * 16 + c15;
#pragma unroll
      for (int r = 0; r < 4; ++r)
        sv[j][r] = accS[j][r] * INV_SQRT_DH_L2E + crw[r] * relLocal[tk - (tq_off + r) + 63];
    }

    float lmax[4];
#pragma unroll
    for (int r = 0; r < 4; ++r)
      lmax[r] = fmaxf(fmaxf(sv[0][r], sv[1][r]), fmaxf(sv[2][r], sv[3][r]));
    int grow = (lmax[0] > mrow[0] + THR_L2E) | (lmax[1] > mrow[1] + THR_L2E) |
               (lmax[2] > mrow[2] + THR_L2E) | (lmax[3] > mrow[3] + THR_L2E);
    if (__any(grow)) {
#pragma unroll
      for (int r = 0; r < 4; ++r) {
        float m = lmax[r];
#pragma unroll
        for (int off = 1; off < 16; off <<= 1) m = fmaxf(m, __shfl_xor(m, off, 64));
        float newm = fmaxf(mrow[r], m);
        float sc = ex2(mrow[r] - newm);
        ssum[r] *= sc;
        mrow[r] = newm;
#pragma unroll
        for (int f = 0; f < 6; ++f) accO[f][r] *= sc;
      }
    }
#pragma unroll
    for (int r = 0; r < 4; ++r) {
      float ps = 0.0f;
#pragma unroll
      for (int j = 0; j < 4; ++j) {
        float p = ex2(sv[j][r] - mrow[r]);
        sv[j][r] = p;
        ps += p;
      }
      ssum[r] += ps;
    }

#pragma unroll
    for (int j = 0; j < 4; ++j)
#pragma unroll
      for (int r = 0; r < 4; ++r)
        pT[wv * 1408 + (g * 4 + r) * 88 + j * 16 + c15] = __float2bfloat16(sv[j][r]);

    bf16x8 ap0 = *(const bf16x8*)&pT[wv * 1408 + c15 * 88 + g * 8];
    bf16x8 ap1 = *(const bf16x8*)&pT[wv * 1408 + c15 * 88 + 32 + g * 8];
    __builtin_amdgcn_s_setprio(1);
#pragma unroll
    for (int f = 0; f < 6; ++f) {
      bf16x8 bv0 = *(const bf16x8*)&vT[(f * 16 + c15) * 88 + g * 8];
      bf16x8 bv1 = *(const bf16x8*)&vT[(f * 16 + c15) * 88 + 32 + g * 8];
      accO[f] = __builtin_amdgcn_mfma_f32_16x16x32_bf16(ap0, bv0, accO[f], 0, 0, 0);
      accO[f] = __builtin_amdgcn_mfma_f32_16x16x32_bf16(ap1, bv1, accO[f], 0, 0, 0);
    }
    __builtin_amdgcn_s_setprio(0);

    if (kt < 15) {
      __hip_bfloat16* kTn = (__hip_bfloat16*)(smem + (cur ^ 1) * 30208);
      __hip_bfloat16* vTn = (__hip_bfloat16*)(smem + (cur ^ 1) * 30208 + 13312);
      *(uint4*)&kTn[kr_ * 104 + kq4 * 24] = nk0;
      *(uint4*)&kTn[kr_ * 104 + kq4 * 24 + 8] = nk1;
      *(uint4*)&kTn[kr_ * 104 + kq4 * 24 + 16] = nk2;
      *(uint4*)&vTn[vrow0 * 88 + vch * 8] = nv0;
      *(uint4*)&vTn[vrow1 * 88 + vch * 8] = nv1;
      *(uint4*)&vTn[vrow2 * 88 + vch * 8] = nv2;
    }
    __syncthreads();
    cur ^= 1;
  }

  float inv[4];
#pragma unroll
  for (int r = 0; r < 4; ++r) {
    float s = ssum[r];
#pragma unroll
    for (int off = 1; off < 16; off <<= 1) s += __shfl_xor(s, off, 64);
    inv[r] = 1.0f / s;
  }
#pragma unroll
  for (int f = 0; f < 6; ++f)
#pragma unroll
    for (int r = 0; r < 4; ++r) {
      int trow = t0 + wv * 16 + g * 4 + r;
      ao[(size_t)(b * Tn + trow) * Dn + h * 96 + f * 16 + c15] =
          __float2bfloat16(accO[f][r] * inv[r]);
    }
}

// ---------------- depthwise conv K=31 ----------------
__global__ __launch_bounds__(256)
void k_dwconv(const float* __restrict__ in, const float* __restrict__ w,
              const float* __restrict__ bias, float* __restrict__ out) {
  __shared__ float tile[94][64];
  __shared__ float wt[64][31];
  __shared__ float bt[64];
  int b = blockIdx.z, t0 = blockIdx.x * 64, d0 = blockIdx.y * 64;
  int tid = threadIdx.x;
  for (int e = tid; e < 94 * 64; e += 256) {
    int rr = e >> 6, dd = e & 63;
    int t = t0 - 15 + rr;
    tile[rr][dd] = (t >= 0 && t < Tn) ? in[(size_t)(b * Tn + t) * Dn + d0 + dd] : 0.0f;
  }
  for (int e = tid; e < 64 * 31; e += 256) {
    int dd = e / 31, k = e - dd * 31;
    wt[dd][k] = w[(d0 + dd) * 31 + k];
  }
  if (tid < 64) bt[tid] = bias[d0 + tid];
  __syncthreads();
  for (int o = tid; o < 64 * 64; o += 256) {
    int tt = o >> 6, dd = o & 63;
    float s = bt[dd];
#pragma unroll
    for (int k = 0; k < 31; ++k) s += tile[tt + k][dd] * wt[dd][k];
    out[(size_t)(b * Tn + t0 + tt) * Dn + d0 + dd] = s;
  }
}

// ---------------- GroupNorm(1,C) ----------------
__global__ void k_gn_part(const float* __restrict__ x, float* __restrict__ part) {
  int b = blockIdx.y, c = blockIdx.x, tid = threadIdx.x;
  const float4* p = (const float4*)(x + (size_t)b * (Dn * Tn) + c * 8192);
  float s = 0.f, q = 0.f;
  for (int i = tid; i < 2048; i += 256) {
    float4 v = p[i];
    s += v.x + v.y + v.z + v.w;
    q += v.x * v.x + v.y * v.y + v.z * v.z + v.w * v.w;
  }
  for (int off = 1; off < 64; off <<= 1) {
    s += __shfl_xor(s, off, 64);
    q += __shfl_xor(q, off, 64);
  }
  __shared__ float ls[4], lq[4];
  int lane = tid & 63, wv = tid >> 6;
  if (lane == 0) { ls[wv] = s; lq[wv] = q; }
  __syncthreads();
  if (tid == 0) {
    part[(b * 96 + c) * 2] = ls[0] + ls[1] + ls[2] + ls[3];
    part[(b * 96 + c) * 2 + 1] = lq[0] + lq[1] + lq[2] + lq[3];
  }
}

__global__ void k_gn_final(const float* __restrict__ part, float* __restrict__ stats) {
  int b = blockIdx.x, tid = threadIdx.x;
  float s = 0.f, q = 0.f;
  if (tid < 96) { s = part[(b * 96 + tid) * 2]; q = part[(b * 96 + tid) * 2 + 1]; }
  for (int off = 1; off < 64; off <<= 1) {
    s += __shfl_xor(s, off, 64);
    q += __shfl_xor(q, off, 64);
  }
  __shared__ float ls[2], lq[2];
  int lane = tid & 63, wv = tid >> 6;
  if (lane == 0) { ls[wv] = s; lq[wv] = q; }
  __syncthreads();
  if (tid == 0) {
    const float N = (float)(Dn * Tn);
    float mean = (ls[0] + ls[1]) / N;
    float var = (lq[0] + lq[1]) / N - mean * mean;
    stats[b * 2] = mean;
    stats[b * 2 + 1] = rsqrtf(var + 1e-5f);
  }
}

// vectorized: 4 elems/thread
template <bool SILU>
__global__ void k_gn_apply(const float* __restrict__ x, const float* __restrict__ stats,
                           const float* __restrict__ w, const float* __restrict__ bb,
                           __hip_bfloat16* __restrict__ out) {
  int i4 = (blockIdx.x * 256 + threadIdx.x) * 4;
  if (i4 >= BT * Dn) return;
  int row = i4 / Dn, d = i4 - row * Dn;
  int b = row >> 10;
  float mean = stats[b * 2], rstd = stats[b * 2 + 1];
  float4 xv = *(const float4*)(x + i4);
  float4 wv4 = *(const float4*)(w + d);
  float4 bv4 = *(const float4*)(bb + d);
  float v0 = (xv.x - mean) * rstd * wv4.x + bv4.x;
  float v1 = (xv.y - mean) * rstd * wv4.y + bv4.y;
  float v2 = (xv.z - mean) * rstd * wv4.z + bv4.z;
  float v3 = (xv.w - mean) * rstd * wv4.w + bv4.w;
  if (SILU) {
    v0 = v0 / (1.0f + ex2(-v0 * L2E));
    v1 = v1 / (1.0f + ex2(-v1 * L2E));
    v2 = v2 / (1.0f + ex2(-v2 * L2E));
    v3 = v3 / (1.0f + ex2(-v3 * L2E));
  }
  union { ushort4 u; __hip_bfloat16 h[4]; } o;
  o.h[0] = __float2bfloat16(v0);
  o.h[1] = __float2bfloat16(v1);
  o.h[2] = __float2bfloat16(v2);
  o.h[3] = __float2bfloat16(v3);
  *(ushort4*)(out + i4) = o.u;
}

// ---------------- launch ----------------
extern "C" void kernel_launch(void* const* d_in, const int* in_sizes, int n_in,
                              void* d_out, int out_size, void* d_ws, size_t ws_size,
                              hipStream_t stream) {
  const float* x         = (const float*)d_in[0];
  const float* w_ff1a    = (const float*)d_in[1];
  const float* b_ff1a    = (const float*)d_in[2];
  const float* w_ff1b    = (const float*)d_in[3];
  const float* b_ff1b    = (const float*)d_in[4];
  const float* w_qkv     = (const float*)d_in[5];
  const float* b_qkv     = (const float*)d_in[6];
  const float* w_out     = (const float*)d_in[7];
  const float* b_out     = (const float*)d_in[8];
  const float* rel_embed = (const float*)d_in[9];
  const float* gate_u    = (const float*)d_in[10];
  const float* gate_w    = (const float*)d_in[11];
  const float* gate_sc   = (const float*)d_in[12];
  const float* gn1_w     = (const float*)d_in[13];
  const float* gn1_b     = (const float*)d_in[14];
  const float* pw1_w     = (const float*)d_in[15];
  const float* pw1_b     = (const float*)d_in[16];
  const float* dw_w      = (const float*)d_in[17];
  const float* dw_b      = (const float*)d_in[18];
  const float* gn2_w     = (const float*)d_in[19];
  const float* gn2_b     = (const float*)d_in[20];
  const float* pw2_w     = (const float*)d_in[21];
  const float* pw2_b     = (const float*)d_in[22];
  const float* w_ff2a    = (const float*)d_in[23];
  const float* b_ff2a    = (const float*)d_in[24];
  const float* w_ff2b    = (const float*)d_in[25];
  const float* b_ff2b    = (const float*)d_in[26];

  char* ws = (char*)d_ws;
  size_t off = 0;
  auto alloc = [&](size_t bytes) {
    void* p = ws + off;
    off = (off + bytes + 255) & ~(size_t)255;
    return p;
  };

  float* SA = (float*)alloc((size_t)BT * Dn * 4);
  float* SB = (float*)alloc((size_t)BT * Dn * 4);
  __hip_bfloat16* ABF = (__hip_bfloat16*)alloc((size_t)BT * Dn * 2);
  void* BIG = alloc((size_t)BT * FFn * 2);
  void* QKV = alloc((size_t)BT * 2304 * 2);
  __hip_bfloat16* Wf1a = (__hip_bfloat16*)alloc((size_t)Dn * FFn * 2);
  __hip_bfloat16* Wf1b = (__hip_bfloat16*)alloc((size_t)Dn * FFn * 2);
  __hip_bfloat16* Wqkv = (__hip_bfloat16*)alloc((size_t)Dn * 2304 * 2);
  __hip_bfloat16* Wout = (__hip_bfloat16*)alloc((size_t)Dn * Dn * 2);
  __hip_bfloat16* Wpw1 = (__hip_bfloat16*)alloc((size_t)1536 * Dn * 2);
  __hip_bfloat16* Wpw2 = (__hip_bfloat16*)alloc((size_t)Dn * Dn * 2);
  __hip_bfloat16* Wf2a = (__hip_bfloat16*)alloc((size_t)Dn * FFn * 2);
  __hip_bfloat16* Wf2b = (__hip_bfloat16*)alloc((size_t)Dn * FFn * 2);
  float* RELT  = (float*)alloc(8 * 2047 * 4);
  float* GPART = (float*)alloc(8 * 96 * 2 * 4);
  float* GSTAT = (float*)alloc(8 * 2 * 4);
  __hip_bfloat16* VT = (__hip_bfloat16*)BIG;
  float* GLUF = (float*)QKV;                       // fp32 overlay (pw1->dwconv)
  __hip_bfloat16* ABF2 = (__hip_bfloat16*)QKV;     // bf16 overlay (pw2 out)
  float* DWO = (float*)d_out;                      // dwconv scratch; overwritten by FF2b-T

  dim3 blk32(32, 8);

  const int PREP_BLOCKS = 2304 + 2304 + 1728 + 576 + 2304 + 2304 + 1152 + 576 + 8;
  k_prep<<<PREP_BLOCKS, 256, 0, stream>>>(
      w_ff1a, w_ff1b, w_qkv, w_out, w_ff2a, w_ff2b, pw1_w, pw2_w, rel_embed,
      Wf1a, Wf1b, Wqkv, Wout, Wf2a, Wf2b, Wpw1, Wpw2, RELT);

  k_tin<<<dim3(Tn / 32, Dn / 32, Bn), blk32, 0, stream>>>(x, SA, ABF);

  // FF1
  k_gemm<128, 128, 1, EPI_GELU><<<dim3(FFn / 128, BT / 128), 256, 0, stream>>>(
      ABF, Wf1a, b_ff1a, nullptr, nullptr, (__hip_bfloat16*)BIG, BT, FFn, Dn);
  k_gemm<64, 128, 2, EPI_HALF_RES><<<dim3(Dn / 128, BT / 64), 256, 0, stream>>>(
      (__hip_bfloat16*)BIG, Wf1b, b_ff1b, SA, SB, ABF, BT, Dn, FFn);

  // QKV
  k_gemm<128, 128, 1, EPI_BIAS><<<dim3(2304 / 128, BT / 128), 256, 0, stream>>>(
      ABF, Wqkv, b_qkv, nullptr, nullptr, (__hip_bfloat16*)QKV, BT, 2304, Dn);

  // V pre-transpose
  k_vtrans<<<dim3(Tn / 32, 3, 64), blk32, 0, stream>>>((const __hip_bfloat16*)QKV, VT);

  // attention -> ABF (bf16)
  k_attn<<<dim3(16, 64), 256, 0, stream>>>((const __hip_bfloat16*)QKV, VT, RELT,
                                           gate_u, gate_w, gate_sc, ABF);

  // out-proj + residual(SB) -> SA
  k_gemm<64, 128, 2, EPI_RES><<<dim3(Dn / 128, BT / 64), 256, 0, stream>>>(
      ABF, Wout, b_out, SB, SA, nullptr, BT, Dn, Dn);

  // GN1(SA) -> ABF
  k_gn_part<<<dim3(96, 8), 256, 0, stream>>>(SA, GPART);
  k_gn_final<<<8, 128, 0, stream>>>(GPART, GSTAT);
  k_gn_apply<false><<<(BT * Dn / 4 + 255) / 256, 256, 0, stream>>>(SA, GSTAT, gn1_w, gn1_b, ABF);

  // pw1 + fused GLU -> GLUF fp32 [BT][768]
  k_gemm<64, 128, 2, EPI_GLU><<<dim3(1536 / 128, BT / 64), 256, 0, stream>>>(
      ABF, Wpw1, pw1_b, nullptr, GLUF, nullptr, BT, 1536, Dn);
  // dwconv -> DWO
  k_dwconv<<<dim3(Tn / 64, Dn / 64, Bn), 256, 0, stream>>>(GLUF, dw_w, dw_b, DWO);
  // GN2 + SiLU -> ABF
  k_gn_part<<<dim3(96, 8), 256, 0, stream>>>(DWO, GPART);
  k_gn_final<<<8, 128, 0, stream>>>(GPART, GSTAT);
  k_gn_apply<true><<<(BT * Dn / 4 + 255) / 256, 256, 0, stream>>>(DWO, GSTAT, gn2_w, gn2_b, ABF);

  // pw2 + residual(SA) -> SB fp32 + ABF2 bf16 (no in-place ABF write: race)
  k_gemm<64, 128, 2, EPI_RES><<<dim3(Dn / 128, BT / 64), 256, 0, stream>>>(
      ABF, Wpw2, pw2_b, SA, SB, ABF2, BT, Dn, Dn);

  // FF2 (reads ABF2); FF2b writes d_out directly (transposed epilogue)
  k_gemm<128, 128, 1, EPI_GELU><<<dim3(FFn / 128, BT / 128), 256, 0, stream>>>(
      ABF2, Wf2a, b_ff2a, nullptr, nullptr, (__hip_bfloat16*)BIG, BT, FFn, Dn);
  k_gemm<64, 128, 2, EPI_HALF_RES_T><<<dim3(Dn / 128, BT / 64), 256, 0, stream>>>(
      (__hip_bfloat16*)BIG, Wf2b, b_ff2b, SB, (float*)d_out, nullptr, BT, Dn, FFn);
}